// Round 9
// baseline (361.284 us; speedup 1.0000x reference)
//
#include <hip/hip_runtime.h>
#include <stdint.h>

#define B_ 4
#define T_ 2048
#define C_ 1024
#define H_ 16
#define D_ 64
#define M_ (B_*T_)      /* 8192 */
#define K_ C_           /* 1024 */

typedef unsigned short ushort_t;
typedef __bf16 bf16x8 __attribute__((ext_vector_type(8)));
typedef float  float4_ __attribute__((ext_vector_type(4)));
typedef ushort_t ushort4_ __attribute__((ext_vector_type(4)));

// hardware f32->bf16 (RNE, v_cvt_pk_bf16_f32 on gfx950)
__device__ __forceinline__ ushort_t cvbf(float f) {
    return __builtin_bit_cast(ushort_t, (__bf16)f);
}
__device__ __forceinline__ float4_ f4zero() { float4_ z; z[0]=0.f; z[1]=0.f; z[2]=0.f; z[3]=0.f; return z; }

// async global->LDS, 16B per lane; LDS dest must be wave-uniform base + lane*16
#define GLDS16(gptr, lptr) \
    __builtin_amdgcn_global_load_lds((const __attribute__((address_space(1))) uint32_t*)(gptr), \
                                     (__attribute__((address_space(3))) uint32_t*)(lptr), 16, 0, 0)

#define QSCALE 0.18033688011112042f   /* 0.125 * log2(e) — exp2-domain softmax */

// ---------------------------------------------------------------------------
// f32 -> bf16 conversion, 4 elements/thread
// ---------------------------------------------------------------------------
__global__ __launch_bounds__(256) void cvt_f32_bf16(const float* __restrict__ src,
                                                    ushort_t* __restrict__ dst) {
    const int i = (blockIdx.x * 256 + threadIdx.x) * 4;
    float4_ v = *(const float4_*)(src + i);
    ushort4_ o;
    #pragma unroll
    for (int e = 0; e < 4; e++) o[e] = cvbf(v[e]);
    *(ushort4_*)(dst + i) = o;
}

// fused 3-matrix cvt: wq|wk|wv (1M elements each) -> wcat [3072][1024]
__global__ __launch_bounds__(256) void cvt3_f32_bf16(const float* __restrict__ s0,
                                                     const float* __restrict__ s1,
                                                     const float* __restrict__ s2,
                                                     ushort_t* __restrict__ dst) {
    const int b = blockIdx.x;                       // 0..3071
    const float* src = (b < 1024) ? s0 : (b < 2048) ? s1 : s2;
    const int off = (b & 1023) * 1024 + threadIdx.x * 4;
    float4_ v = *(const float4_*)(src + off);
    ushort4_ o;
    #pragma unroll
    for (int e = 0; e < 4; e++) o[e] = cvbf(v[e]);
    *(ushort4_*)(dst + (size_t)b * 1024 + threadIdx.x * 4) = o;
}

// ---------------------------------------------------------------------------
// w_o f32 [1024(hd)][1024(c)] -> wot bf16 [1024(c)][1024(hd)]
// ---------------------------------------------------------------------------
__global__ __launch_bounds__(256) void transpose_wo(const float* __restrict__ wo,
                                                    ushort_t* __restrict__ wot) {
    __shared__ ushort_t tile[64][65];
    const int c0 = (blockIdx.x & 15) * 64;
    const int r0 = (blockIdx.x >> 4) * 64;   // hd tile base
    const int tid = threadIdx.x;
    const int row = tid >> 2;                // 64 rows, 4 threads/row
    const int col = (tid & 3) * 16;
    #pragma unroll
    for (int r = 0; r < 4; r++) {
        float4_ v = *(const float4_*)(wo + (size_t)(r0 + row) * 1024 + c0 + col + r * 4);
        #pragma unroll
        for (int e = 0; e < 4; e++) tile[row][col + r * 4 + e] = cvbf(v[e]);
    }
    __syncthreads();
    #pragma unroll
    for (int r = 0; r < 2; r++) {
        bf16x8 v;
        #pragma unroll
        for (int e = 0; e < 8; e++) v[e] = __builtin_bit_cast(__bf16, tile[col + r * 8 + e][row]);
        *(bf16x8*)(wot + (size_t)(c0 + row) * 1024 + r0 + col + r * 8) = v;
    }
}

// ---------------------------------------------------------------------------
// GEMM: C[M x N] = A[M x K] * Bt[N x K]^T  (bf16 in, fp32 acc)
// Staging via global_load_lds width=16.
// MODE 0: Bt = Wcat [3072 x 1024]; Q (xQSCALE) [nh][t][d], K [nh][t][d];
//         V-blocks run SWAPPED-operand MFMA (acc = D^T) so the vt_ws [d][t]
//         store is lane-contiguous in t (validated round 8, ~7 us win).
// MODE 1: Bt = wot [1024 x 1024]; f32 store to d_out
// ---------------------------------------------------------------------------
template<int MODE>
__global__ __launch_bounds__(256)
void gemm_bt(const ushort_t* __restrict__ A,
             const ushort_t* __restrict__ Bt,
             ushort_t* __restrict__ q_ws, ushort_t* __restrict__ k_ws,
             ushort_t* __restrict__ vt_ws, float* __restrict__ outp)
{
    __shared__ __align__(16) ushort_t As[128 * 32];
    __shared__ __align__(16) ushort_t Bs[128 * 32];
    const int tid = threadIdx.x;
    const int m0 = blockIdx.x * 128;
    const int n0 = blockIdx.y * 128;

    const int L    = tid & 63;
    const int wid  = tid >> 6;
    const int wr   = (wid >> 1) * 64;
    const int wc   = (wid & 1) * 64;
    const int quad = L >> 4;
    const int lc   = L & 15;
    const int mat  = (MODE == 0) ? (n0 >> 10) : 0;   // which of q/k/v
    const bool vswap = (MODE == 0) && (mat == 2);

    float4_ acc[4][4];
    #pragma unroll
    for (int i = 0; i < 4; i++)
        #pragma unroll
        for (int j = 0; j < 4; j++) acc[i][j] = f4zero();

    const int loff0 = wid * 1024 + L * 16;   // per-lane byte offset = wave-base + lane*16
    for (int k0 = 0; k0 < K_; k0 += 32) {
        __syncthreads();
        #pragma unroll
        for (int r = 0; r < 2; r++) {
            const int off = loff0 + r * 4096;
            const int row = off >> 6;    // 64 B per tile row (32 bf16)
            const int col = off & 63;    // byte col
            const char* ga = (const char*)A  + (size_t)(m0 + row) * (K_ * 2) + k0 * 2 + col;
            const char* gb = (const char*)Bt + (size_t)(n0 + row) * (K_ * 2) + k0 * 2 + col;
            GLDS16(ga, (char*)As + off);
            GLDS16(gb, (char*)Bs + off);
        }
        __syncthreads();
        bf16x8 af[4], bfr[4];
        #pragma unroll
        for (int i = 0; i < 4; i++) {
            const int m = wr + i * 16 + lc;
            af[i]  = *(const bf16x8*)((const char*)As + m * 64 + quad * 16);
            const int n = wc + i * 16 + lc;
            bfr[i] = *(const bf16x8*)((const char*)Bs + n * 64 + quad * 16);
        }
        if (vswap) {
            #pragma unroll
            for (int i = 0; i < 4; i++)
                #pragma unroll
                for (int j = 0; j < 4; j++)
                    acc[i][j] = __builtin_amdgcn_mfma_f32_16x16x32_bf16(bfr[j], af[i], acc[i][j], 0, 0, 0);
        } else {
            #pragma unroll
            for (int i = 0; i < 4; i++)
                #pragma unroll
                for (int j = 0; j < 4; j++)
                    acc[i][j] = __builtin_amdgcn_mfma_f32_16x16x32_bf16(af[i], bfr[j], acc[i][j], 0, 0, 0);
        }
    }

    // epilogue: C/D layout col=lane&15, row=quad*4+reg (m89-verified)
    const int nb = n0 & 1023;
    #pragma unroll
    for (int i = 0; i < 4; i++) {
        #pragma unroll
        for (int j = 0; j < 4; j++) {
            #pragma unroll
            for (int rg = 0; rg < 4; rg++) {
                const float v = acc[i][j][rg];
                if (MODE == 1) {
                    const int mg = m0 + wr + i * 16 + quad * 4 + rg;
                    const int cg = n0 + wc + j * 16 + lc;
                    outp[(size_t)mg * 1024 + cg] = v;          // f32 store
                } else if (vswap) {
                    // D^T: col=lc -> m (t), row=quad*4+rg -> n (weight d)
                    const int mg = m0 + wr + i * 16 + lc;
                    const int ln = nb + wc + j * 16 + quad * 4 + rg;
                    const int h = ln >> 6, d = ln & 63;
                    const int n = mg >> 11, t = mg & 2047;
                    const int nh = n * H_ + h;
                    vt_ws[((size_t)nh * 64 + d) * T_ + t] = cvbf(v);   // lc-contig in t
                } else {
                    const int mg = m0 + wr + i * 16 + quad * 4 + rg;
                    const int ln = nb + wc + j * 16 + lc;
                    const int h = ln >> 6, d = ln & 63;
                    const int n = mg >> 11, t = mg & 2047;
                    const int nh = n * H_ + h;
                    if (mat == 0) q_ws[((size_t)nh * T_ + t) * 64 + d] = cvbf(v * QSCALE);
                    else          k_ws[((size_t)nh * T_ + t) * 64 + d] = cvbf(v);
                }
            }
        }
    }
}

// ---------------------------------------------------------------------------
// MFMA flash attention, transposed formulation (round-7 structure, reverted):
//   S^T = K Q^T ; O^T = V^T P^T ; per-lane scalar softmax state.
// Q pre-scaled by log2(e)/8 -> softmax in exp2 domain (bare v_exp_f32).
// 1 block = (n,h, 64-row q-tile); 4 waves x 16 q-rows. LDS pitch 72 (144 B).
// Occupancy note (r8 lesson): 64-row/VGPR-64/27.6KB = 5 blocks/CU beats any
// reuse gain that costs a resident block.
// ---------------------------------------------------------------------------
#define KP 72   /* padded row pitch, elements */

__global__ __launch_bounds__(256)
void attn(const ushort_t* __restrict__ q_ws, const ushort_t* __restrict__ k_ws,
          const ushort_t* __restrict__ vt_ws, ushort_t* __restrict__ y_ws)
{
    __shared__ __align__(16) ushort_t Ks[64 * KP];      // [s][d], padded
    __shared__ __align__(16) ushort_t Vs[64 * KP];      // [d][s], padded
    __shared__ __align__(16) ushort_t Ps[4][16 * KP];   // per-wave P^T as [t][s]
    const int tid  = threadIdx.x;
    const int L    = tid & 63;
    const int w    = tid >> 6;
    const int quad = L >> 4, lc = L & 15;
    const int bid  = blockIdx.x;
    const int qt   = 31 - (bid & 31);    // heavy blocks first (tail balance)
    const int nh   = bid >> 5;
    const int n    = nh >> 4;
    const int tq0  = qt * 64 + w * 16;
    const int tg   = tq0 + lc;           // this lane's q-row

    // Q fragments (B-operand layout [n=t=lc][k=d=quad*8+j]):
    const ushort_t* qbase = q_ws + ((size_t)nh * T_ + tq0) * 64;
    const bf16x8 qf0 = *(const bf16x8*)(qbase + (size_t)lc * 64 + quad * 8);
    const bf16x8 qf1 = *(const bf16x8*)(qbase + (size_t)lc * 64 + quad * 8 + 32);

    float m_i = -1e30f, l_i = 0.f;       // per-lane scalars (q-row tg), log2 domain
    float4_ o[4];                        // O^T C-layout: col=t (lane), row=d
    #pragma unroll
    for (int r = 0; r < 4; r++) o[r] = f4zero();

    const ushort_t* kbase = k_ws  + (size_t)nh * T_ * 64;   // [t][d]
    const ushort_t* vbase = vt_ws + (size_t)nh * 64 * T_;   // [d][t]
    ushort_t* pw = Ps[w];

    for (int st = 0; st <= qt; st++) {
        // stage K [s][d] and Vt [d][s] tiles; each thread 16 B x2 per array
        #pragma unroll
        for (int r = 0; r < 2; r++) {
            const int off = tid * 16 + r * 4096;   // logical offset in 64x128B tile
            const int row = off >> 7;
            const int col = off & 127;
            bf16x8 kv = *(const bf16x8*)((const char*)kbase + (size_t)(st * 64 + row) * 128 + col);
            bf16x8 vv = *(const bf16x8*)((const char*)vbase + (size_t)row * (T_ * 2) + st * 128 + col);
            *(bf16x8*)((char*)Ks + row * (KP * 2) + col) = kv;
            *(bf16x8*)((char*)Vs + row * (KP * 2) + col) = vv;
        }
        __syncthreads();

        // S^T = K Q^T: 4 s-blocks of 16; D[s][t]: row=quad*4+rg -> s, col=lc -> t
        float4_ s[4];
        #pragma unroll
        for (int sb = 0; sb < 4; sb++) {
            const int srow = sb * 16 + lc;
            const bf16x8 kf0 = *(const bf16x8*)((const char*)Ks + srow * (KP * 2) + quad * 16);
            const bf16x8 kf1 = *(const bf16x8*)((const char*)Ks + srow * (KP * 2) + 64 + quad * 16);
            float4_ a = f4zero();
            a = __builtin_amdgcn_mfma_f32_16x16x32_bf16(kf0, qf0, a, 0, 0, 0);
            a = __builtin_amdgcn_mfma_f32_16x16x32_bf16(kf1, qf1, a, 0, 0, 0);
            s[sb] = a;
        }
        if (st == qt) {   // causal mask on diagonal tile: s_global > t_global
            #pragma unroll
            for (int sb = 0; sb < 4; sb++)
                #pragma unroll
                for (int rg = 0; rg < 4; rg++) {
                    const int sg = st * 64 + sb * 16 + quad * 4 + rg;
                    if (sg > tg) s[sb][rg] = -1e30f;
                }
        }
        // online softmax (exp2 domain), per-lane: 16 in-register scores
        float rm = -1e30f;
        #pragma unroll
        for (int sb = 0; sb < 4; sb++)
            #pragma unroll
            for (int rg = 0; rg < 4; rg++) rm = fmaxf(rm, s[sb][rg]);
        rm = fmaxf(rm, __shfl_xor(rm, 16));
        rm = fmaxf(rm, __shfl_xor(rm, 32));
        const float mn    = fmaxf(m_i, rm);
        const float alpha = __builtin_exp2f(m_i - mn);
        float rs = 0.f;
        #pragma unroll
        for (int sb = 0; sb < 4; sb++)
            #pragma unroll
            for (int rg = 0; rg < 4; rg++) {
                const float p = __builtin_exp2f(s[sb][rg] - mn);
                s[sb][rg] = p;
                rs += p;
            }
        rs += __shfl_xor(rs, 16);
        rs += __shfl_xor(rs, 32);
        l_i = l_i * alpha + rs;
        m_i = mn;
        #pragma unroll
        for (int db = 0; db < 4; db++)
            #pragma unroll
            for (int rg = 0; rg < 4; rg++) o[db][rg] *= alpha;

        // P^T -> LDS as [t][s]; rg-values are s-contiguous -> one b64 per sb
        #pragma unroll
        for (int sb = 0; sb < 4; sb++) {
            ushort4_ pk;
            #pragma unroll
            for (int rg = 0; rg < 4; rg++) pk[rg] = cvbf(s[sb][rg]);
            *(ushort4_*)(pw + lc * KP + sb * 16 + quad * 4) = pk;
        }

        // O^T += V^T P^T: A = Vs row d [k=s], B = Pb row t [k=s]
        const bf16x8 pa0 = *(const bf16x8*)((const char*)pw + lc * (KP * 2) + quad * 16);
        const bf16x8 pa1 = *(const bf16x8*)((const char*)pw + lc * (KP * 2) + 64 + quad * 16);
        #pragma unroll
        for (int db = 0; db < 4; db++) {
            const int d = db * 16 + lc;
            const bf16x8 vf0 = *(const bf16x8*)((const char*)Vs + d * (KP * 2) + quad * 16);
            const bf16x8 vf1 = *(const bf16x8*)((const char*)Vs + d * (KP * 2) + 64 + quad * 16);
            o[db] = __builtin_amdgcn_mfma_f32_16x16x32_bf16(vf0, pa0, o[db], 0, 0, 0);
            o[db] = __builtin_amdgcn_mfma_f32_16x16x32_bf16(vf1, pa1, o[db], 0, 0, 0);
        }
        __syncthreads();   // all waves done with Ks/Vs before next stage
    }

    // epilogue: O^T lane owns q-row tg; d = db*16 + quad*4 + rg (4 consecutive)
    const int h = nh & 15;
    const float inv = 1.f / l_i;
    ushort_t* yrow = y_ws + ((size_t)(n * T_ + tg)) * 1024 + h * 64;
    #pragma unroll
    for (int db = 0; db < 4; db++) {
        ushort4_ pk;
        #pragma unroll
        for (int rg = 0; rg < 4; rg++) pk[rg] = cvbf(o[db][rg] * inv);
        *(ushort4_*)(yrow + db * 16 + quad * 4) = pk;
    }
}

// ---------------------------------------------------------------------------
extern "C" void kernel_launch(void* const* d_in, const int* in_sizes, int n_in,
                              void* d_out, int out_size, void* d_ws, size_t ws_size,
                              hipStream_t stream) {
    (void)in_sizes; (void)n_in; (void)out_size; (void)ws_size;
    const float* x  = (const float*)d_in[0];
    const float* wq = (const float*)d_in[1];
    const float* wk = (const float*)d_in[2];
    const float* wv = (const float*)d_in[3];
    const float* wo = (const float*)d_in[4];
    char* ws = (char*)d_ws;
    const size_t MB = (size_t)1024 * 1024;
    ushort_t* x_bf  = (ushort_t*)(ws);            // 16 MB; reused as y after attn
    ushort_t* q_ws  = (ushort_t*)(ws + 16 * MB);  // 16 MB
    ushort_t* k_ws  = (ushort_t*)(ws + 32 * MB);  // 16 MB
    ushort_t* vt_ws = (ushort_t*)(ws + 48 * MB);  // 16 MB
    ushort_t* wcat  = (ushort_t*)(ws + 64 * MB);  // 6 MB  [3072][1024]
    ushort_t* wot   = (ushort_t*)(ws + 70 * MB);  // 2 MB  [1024(c)][1024(hd)]
    ushort_t* y_ws  = x_bf;                       // safe: attn never reads x_bf
    float*    outp  = (float*)d_out;              // f32 output

    cvt_f32_bf16<<<dim3(8192), dim3(256), 0, stream>>>(x, x_bf);
    cvt3_f32_bf16<<<dim3(3072), dim3(256), 0, stream>>>(wq, wk, wv, wcat);
    transpose_wo<<<dim3(256), dim3(256), 0, stream>>>(wo, wot);
    gemm_bt<0><<<dim3(64, 24), dim3(256), 0, stream>>>(x_bf, wcat, q_ws, k_ws, vt_ws, nullptr);
    attn<<<dim3(2048), dim3(256), 0, stream>>>(q_ws, k_ws, vt_ws, y_ws);
    gemm_bt<1><<<dim3(64, 8), dim3(256), 0, stream>>>(y_ws, wot, nullptr, nullptr, nullptr, outp);
}

// Round 10
// 339.953 us; speedup vs baseline: 1.0627x; 1.0627x over previous
//
#include <hip/hip_runtime.h>
#include <stdint.h>

#define B_ 4
#define T_ 2048
#define C_ 1024
#define H_ 16
#define D_ 64
#define M_ (B_*T_)      /* 8192 */
#define K_ C_           /* 1024 */

typedef unsigned short ushort_t;
typedef __bf16 bf16x8 __attribute__((ext_vector_type(8)));
typedef float  float4_ __attribute__((ext_vector_type(4)));
typedef ushort_t ushort4_ __attribute__((ext_vector_type(4)));

// manual f32->bf16 RNE (4 VALU ops) — keep: the (__bf16) cast pushed attn
// to 68 VGPR / -18% perf in r9 (64-VGPR occupancy cliff, m69)
__device__ __forceinline__ ushort_t f2bf(float f) {
    union { float f; uint32_t u; } c; c.f = f;
    uint32_t u = c.u;
    uint32_t r = (u + 0x7FFFu + ((u >> 16) & 1u)) >> 16;
    return (ushort_t)r;
}
__device__ __forceinline__ float4_ f4zero() { float4_ z; z[0]=0.f; z[1]=0.f; z[2]=0.f; z[3]=0.f; return z; }

// async global->LDS, 16B per lane; LDS dest must be wave-uniform base + lane*16
#define GLDS16(gptr, lptr) \
    __builtin_amdgcn_global_load_lds((const __attribute__((address_space(1))) uint32_t*)(gptr), \
                                     (__attribute__((address_space(3))) uint32_t*)(lptr), 16, 0, 0)

// ---------------------------------------------------------------------------
// f32 -> bf16 conversion, 4 elements/thread
// ---------------------------------------------------------------------------
__global__ __launch_bounds__(256) void cvt_f32_bf16(const float* __restrict__ src,
                                                    ushort_t* __restrict__ dst) {
    const int i = (blockIdx.x * 256 + threadIdx.x) * 4;
    float4_ v = *(const float4_*)(src + i);
    ushort4_ o;
    #pragma unroll
    for (int e = 0; e < 4; e++) o[e] = f2bf(v[e]);
    *(ushort4_*)(dst + i) = o;
}

// fused 3-matrix cvt: wq|wk|wv (1M elements each) -> wcat [3072][1024]
__global__ __launch_bounds__(256) void cvt3_f32_bf16(const float* __restrict__ s0,
                                                     const float* __restrict__ s1,
                                                     const float* __restrict__ s2,
                                                     ushort_t* __restrict__ dst) {
    const int b = blockIdx.x;                       // 0..3071
    const float* src = (b < 1024) ? s0 : (b < 2048) ? s1 : s2;
    const int off = (b & 1023) * 1024 + threadIdx.x * 4;
    float4_ v = *(const float4_*)(src + off);
    ushort4_ o;
    #pragma unroll
    for (int e = 0; e < 4; e++) o[e] = f2bf(v[e]);
    *(ushort4_*)(dst + (size_t)b * 1024 + threadIdx.x * 4) = o;
}

// ---------------------------------------------------------------------------
// w_o f32 [1024(hd)][1024(c)] -> wot bf16 [1024(c)][1024(hd)]
// ---------------------------------------------------------------------------
__global__ __launch_bounds__(256) void transpose_wo(const float* __restrict__ wo,
                                                    ushort_t* __restrict__ wot) {
    __shared__ ushort_t tile[64][65];
    const int c0 = (blockIdx.x & 15) * 64;
    const int r0 = (blockIdx.x >> 4) * 64;   // hd tile base
    const int tid = threadIdx.x;
    const int row = tid >> 2;                // 64 rows, 4 threads/row
    const int col = (tid & 3) * 16;
    #pragma unroll
    for (int r = 0; r < 4; r++) {
        float4_ v = *(const float4_*)(wo + (size_t)(r0 + row) * 1024 + c0 + col + r * 4);
        #pragma unroll
        for (int e = 0; e < 4; e++) tile[row][col + r * 4 + e] = f2bf(v[e]);
    }
    __syncthreads();
    #pragma unroll
    for (int r = 0; r < 2; r++) {
        bf16x8 v;
        #pragma unroll
        for (int e = 0; e < 8; e++) v[e] = __builtin_bit_cast(__bf16, tile[col + r * 8 + e][row]);
        *(bf16x8*)(wot + (size_t)(c0 + row) * 1024 + r0 + col + r * 8) = v;
    }
}

// ---------------------------------------------------------------------------
// GEMM: C[M x N] = A[M x K] * Bt[N x K]^T  (bf16 in, fp32 acc)
// Staging via global_load_lds width=16.
// MODE 0: Bt = Wcat [3072 x 1024]; Q (x0.125) [nh][t][d], K [nh][t][d];
//         V-blocks run SWAPPED-operand MFMA (acc = D^T) so the vt_ws [d][t]
//         store is lane-contiguous in t (validated round 8, ~7 us win).
// MODE 1: Bt = wot [1024 x 1024]; f32 store to d_out
// ---------------------------------------------------------------------------
template<int MODE>
__global__ __launch_bounds__(256)
void gemm_bt(const ushort_t* __restrict__ A,
             const ushort_t* __restrict__ Bt,
             ushort_t* __restrict__ q_ws, ushort_t* __restrict__ k_ws,
             ushort_t* __restrict__ vt_ws, float* __restrict__ outp)
{
    __shared__ __align__(16) ushort_t As[128 * 32];
    __shared__ __align__(16) ushort_t Bs[128 * 32];
    const int tid = threadIdx.x;
    const int m0 = blockIdx.x * 128;
    const int n0 = blockIdx.y * 128;

    const int L    = tid & 63;
    const int wid  = tid >> 6;
    const int wr   = (wid >> 1) * 64;
    const int wc   = (wid & 1) * 64;
    const int quad = L >> 4;
    const int lc   = L & 15;
    const int mat  = (MODE == 0) ? (n0 >> 10) : 0;   // which of q/k/v
    const bool vswap = (MODE == 0) && (mat == 2);

    float4_ acc[4][4];
    #pragma unroll
    for (int i = 0; i < 4; i++)
        #pragma unroll
        for (int j = 0; j < 4; j++) acc[i][j] = f4zero();

    const int loff0 = wid * 1024 + L * 16;   // per-lane byte offset = wave-base + lane*16
    for (int k0 = 0; k0 < K_; k0 += 32) {
        __syncthreads();
        #pragma unroll
        for (int r = 0; r < 2; r++) {
            const int off = loff0 + r * 4096;
            const int row = off >> 6;    // 64 B per tile row (32 bf16)
            const int col = off & 63;    // byte col
            const char* ga = (const char*)A  + (size_t)(m0 + row) * (K_ * 2) + k0 * 2 + col;
            const char* gb = (const char*)Bt + (size_t)(n0 + row) * (K_ * 2) + k0 * 2 + col;
            GLDS16(ga, (char*)As + off);
            GLDS16(gb, (char*)Bs + off);
        }
        __syncthreads();
        bf16x8 af[4], bfr[4];
        #pragma unroll
        for (int i = 0; i < 4; i++) {
            const int m = wr + i * 16 + lc;
            af[i]  = *(const bf16x8*)((const char*)As + m * 64 + quad * 16);
            const int n = wc + i * 16 + lc;
            bfr[i] = *(const bf16x8*)((const char*)Bs + n * 64 + quad * 16);
        }
        if (vswap) {
            #pragma unroll
            for (int i = 0; i < 4; i++)
                #pragma unroll
                for (int j = 0; j < 4; j++)
                    acc[i][j] = __builtin_amdgcn_mfma_f32_16x16x32_bf16(bfr[j], af[i], acc[i][j], 0, 0, 0);
        } else {
            #pragma unroll
            for (int i = 0; i < 4; i++)
                #pragma unroll
                for (int j = 0; j < 4; j++)
                    acc[i][j] = __builtin_amdgcn_mfma_f32_16x16x32_bf16(af[i], bfr[j], acc[i][j], 0, 0, 0);
        }
    }

    // epilogue: C/D layout col=lane&15, row=quad*4+reg (m89-verified)
    const int nb = n0 & 1023;
    #pragma unroll
    for (int i = 0; i < 4; i++) {
        #pragma unroll
        for (int j = 0; j < 4; j++) {
            #pragma unroll
            for (int rg = 0; rg < 4; rg++) {
                const float v = acc[i][j][rg];
                if (MODE == 1) {
                    const int mg = m0 + wr + i * 16 + quad * 4 + rg;
                    const int cg = n0 + wc + j * 16 + lc;
                    outp[(size_t)mg * 1024 + cg] = v;          // f32 store
                } else if (vswap) {
                    // D^T: col=lc -> m (t), row=quad*4+rg -> n (weight d)
                    const int mg = m0 + wr + i * 16 + lc;
                    const int ln = nb + wc + j * 16 + quad * 4 + rg;
                    const int h = ln >> 6, d = ln & 63;
                    const int n = mg >> 11, t = mg & 2047;
                    const int nh = n * H_ + h;
                    vt_ws[((size_t)nh * 64 + d) * T_ + t] = f2bf(v);   // lc-contig in t
                } else {
                    const int mg = m0 + wr + i * 16 + quad * 4 + rg;
                    const int ln = nb + wc + j * 16 + lc;
                    const int h = ln >> 6, d = ln & 63;
                    const int n = mg >> 11, t = mg & 2047;
                    const int nh = n * H_ + h;
                    if (mat == 0) q_ws[((size_t)nh * T_ + t) * 64 + d] = f2bf(v * 0.125f);
                    else          k_ws[((size_t)nh * T_ + t) * 64 + d] = f2bf(v);
                }
            }
        }
    }
}

// ---------------------------------------------------------------------------
// MFMA flash attention — EXACT round-7 structure (148.8 us, VGPR 64):
//   S^T = K Q^T ; O^T = V^T P^T ; per-lane scalar softmax state, __expf.
// 1 block = (n,h, 64-row q-tile); 4 waves x 16 q-rows. LDS pitch 72 (144 B).
// r8/r9 lessons: do NOT trade occupancy for reuse; VGPR=64 is a cliff.
// ---------------------------------------------------------------------------
#define KP 72   /* padded row pitch, elements */

__global__ __launch_bounds__(256)
void attn(const ushort_t* __restrict__ q_ws, const ushort_t* __restrict__ k_ws,
          const ushort_t* __restrict__ vt_ws, ushort_t* __restrict__ y_ws)
{
    __shared__ __align__(16) ushort_t Ks[64 * KP];      // [s][d], padded
    __shared__ __align__(16) ushort_t Vs[64 * KP];      // [d][s], padded
    __shared__ __align__(16) ushort_t Ps[4][16 * KP];   // per-wave P^T as [t][s]
    const int tid  = threadIdx.x;
    const int L    = tid & 63;
    const int w    = tid >> 6;
    const int quad = L >> 4, lc = L & 15;
    const int bid  = blockIdx.x;
    const int qt   = 31 - (bid & 31);    // heavy blocks first (tail balance)
    const int nh   = bid >> 5;
    const int n    = nh >> 4;
    const int tq0  = qt * 64 + w * 16;
    const int tg   = tq0 + lc;           // this lane's q-row

    // Q fragments (B-operand layout [n=t=lc][k=d=quad*8+j]):
    const ushort_t* qbase = q_ws + ((size_t)nh * T_ + tq0) * 64;
    const bf16x8 qf0 = *(const bf16x8*)(qbase + (size_t)lc * 64 + quad * 8);
    const bf16x8 qf1 = *(const bf16x8*)(qbase + (size_t)lc * 64 + quad * 8 + 32);

    float m_i = -1e30f, l_i = 0.f;       // per-lane scalars (q-row tg)
    float4_ o[4];                        // O^T C-layout: col=t (lane), row=d
    #pragma unroll
    for (int r = 0; r < 4; r++) o[r] = f4zero();

    const ushort_t* kbase = k_ws  + (size_t)nh * T_ * 64;   // [t][d]
    const ushort_t* vbase = vt_ws + (size_t)nh * 64 * T_;   // [d][t]
    ushort_t* pw = Ps[w];

    for (int st = 0; st <= qt; st++) {
        // stage K [s][d] and Vt [d][s] tiles; each thread 16 B x2 per array
        #pragma unroll
        for (int r = 0; r < 2; r++) {
            const int off = tid * 16 + r * 4096;   // logical offset in 64x128B tile
            const int row = off >> 7;
            const int col = off & 127;
            bf16x8 kv = *(const bf16x8*)((const char*)kbase + (size_t)(st * 64 + row) * 128 + col);
            bf16x8 vv = *(const bf16x8*)((const char*)vbase + (size_t)row * (T_ * 2) + st * 128 + col);
            *(bf16x8*)((char*)Ks + row * (KP * 2) + col) = kv;
            *(bf16x8*)((char*)Vs + row * (KP * 2) + col) = vv;
        }
        __syncthreads();

        // S^T = K Q^T: 4 s-blocks of 16; D[s][t]: row=quad*4+rg -> s, col=lc -> t
        float4_ s[4];
        #pragma unroll
        for (int sb = 0; sb < 4; sb++) {
            const int srow = sb * 16 + lc;
            const bf16x8 kf0 = *(const bf16x8*)((const char*)Ks + srow * (KP * 2) + quad * 16);
            const bf16x8 kf1 = *(const bf16x8*)((const char*)Ks + srow * (KP * 2) + 64 + quad * 16);
            float4_ a = f4zero();
            a = __builtin_amdgcn_mfma_f32_16x16x32_bf16(kf0, qf0, a, 0, 0, 0);
            a = __builtin_amdgcn_mfma_f32_16x16x32_bf16(kf1, qf1, a, 0, 0, 0);
            s[sb] = a;
        }
        if (st == qt) {   // causal mask on diagonal tile: s_global > t_global
            #pragma unroll
            for (int sb = 0; sb < 4; sb++)
                #pragma unroll
                for (int rg = 0; rg < 4; rg++) {
                    const int sg = st * 64 + sb * 16 + quad * 4 + rg;
                    if (sg > tg) s[sb][rg] = -1e30f;
                }
        }
        // online softmax, per-lane: 16 in-register scores for q-row tg
        float rm = -1e30f;
        #pragma unroll
        for (int sb = 0; sb < 4; sb++)
            #pragma unroll
            for (int rg = 0; rg < 4; rg++) rm = fmaxf(rm, s[sb][rg]);
        rm = fmaxf(rm, __shfl_xor(rm, 16));
        rm = fmaxf(rm, __shfl_xor(rm, 32));
        const float mn    = fmaxf(m_i, rm);
        const float alpha = __expf(m_i - mn);
        float rs = 0.f;
        #pragma unroll
        for (int sb = 0; sb < 4; sb++)
            #pragma unroll
            for (int rg = 0; rg < 4; rg++) {
                const float p = __expf(s[sb][rg] - mn);
                s[sb][rg] = p;
                rs += p;
            }
        rs += __shfl_xor(rs, 16);
        rs += __shfl_xor(rs, 32);
        l_i = l_i * alpha + rs;
        m_i = mn;
        #pragma unroll
        for (int db = 0; db < 4; db++)
            #pragma unroll
            for (int rg = 0; rg < 4; rg++) o[db][rg] *= alpha;

        // P^T -> LDS as [t][s]; rg-values are s-contiguous -> one b64 per sb
        #pragma unroll
        for (int sb = 0; sb < 4; sb++) {
            ushort4_ pk;
            #pragma unroll
            for (int rg = 0; rg < 4; rg++) pk[rg] = f2bf(s[sb][rg]);
            *(ushort4_*)(pw + lc * KP + sb * 16 + quad * 4) = pk;
        }

        // O^T += V^T P^T: A = Vs row d [k=s], B = Pb row t [k=s]
        const bf16x8 pa0 = *(const bf16x8*)((const char*)pw + lc * (KP * 2) + quad * 16);
        const bf16x8 pa1 = *(const bf16x8*)((const char*)pw + lc * (KP * 2) + 64 + quad * 16);
        #pragma unroll
        for (int db = 0; db < 4; db++) {
            const int d = db * 16 + lc;
            const bf16x8 vf0 = *(const bf16x8*)((const char*)Vs + d * (KP * 2) + quad * 16);
            const bf16x8 vf1 = *(const bf16x8*)((const char*)Vs + d * (KP * 2) + 64 + quad * 16);
            o[db] = __builtin_amdgcn_mfma_f32_16x16x32_bf16(vf0, pa0, o[db], 0, 0, 0);
            o[db] = __builtin_amdgcn_mfma_f32_16x16x32_bf16(vf1, pa1, o[db], 0, 0, 0);
        }
        __syncthreads();   // all waves done with Ks/Vs before next stage
    }

    // epilogue: O^T lane owns q-row tg; d = db*16 + quad*4 + rg (4 consecutive)
    const int h = nh & 15;
    const float inv = 1.f / l_i;
    ushort_t* yrow = y_ws + ((size_t)(n * T_ + tg)) * 1024 + h * 64;
    #pragma unroll
    for (int db = 0; db < 4; db++) {
        ushort4_ pk;
        #pragma unroll
        for (int rg = 0; rg < 4; rg++) pk[rg] = f2bf(o[db][rg] * inv);
        *(ushort4_*)(yrow + db * 16 + quad * 4) = pk;
    }
}

// ---------------------------------------------------------------------------
extern "C" void kernel_launch(void* const* d_in, const int* in_sizes, int n_in,
                              void* d_out, int out_size, void* d_ws, size_t ws_size,
                              hipStream_t stream) {
    (void)in_sizes; (void)n_in; (void)out_size; (void)ws_size;
    const float* x  = (const float*)d_in[0];
    const float* wq = (const float*)d_in[1];
    const float* wk = (const float*)d_in[2];
    const float* wv = (const float*)d_in[3];
    const float* wo = (const float*)d_in[4];
    char* ws = (char*)d_ws;
    const size_t MB = (size_t)1024 * 1024;
    ushort_t* x_bf  = (ushort_t*)(ws);            // 16 MB; reused as y after attn
    ushort_t* q_ws  = (ushort_t*)(ws + 16 * MB);  // 16 MB
    ushort_t* k_ws  = (ushort_t*)(ws + 32 * MB);  // 16 MB
    ushort_t* vt_ws = (ushort_t*)(ws + 48 * MB);  // 16 MB
    ushort_t* wcat  = (ushort_t*)(ws + 64 * MB);  // 6 MB  [3072][1024]
    ushort_t* wot   = (ushort_t*)(ws + 70 * MB);  // 2 MB  [1024(c)][1024(hd)]
    ushort_t* y_ws  = x_bf;                       // safe: attn never reads x_bf
    float*    outp  = (float*)d_out;              // f32 output

    cvt_f32_bf16<<<dim3(8192), dim3(256), 0, stream>>>(x, x_bf);
    cvt3_f32_bf16<<<dim3(3072), dim3(256), 0, stream>>>(wq, wk, wv, wcat);
    transpose_wo<<<dim3(256), dim3(256), 0, stream>>>(wo, wot);
    gemm_bt<0><<<dim3(64, 24), dim3(256), 0, stream>>>(x_bf, wcat, q_ws, k_ws, vt_ws, nullptr);
    attn<<<dim3(2048), dim3(256), 0, stream>>>(q_ws, k_ws, vt_ws, y_ws);
    gemm_bt<1><<<dim3(64, 8), dim3(256), 0, stream>>>(y_ws, wot, nullptr, nullptr, nullptr, outp);
}